// Round 1
// baseline (2085.374 us; speedup 1.0000x reference)
//
#include <hip/hip_runtime.h>
#include <hip/hip_fp16.h>

#define HEADS 16
#define DM 1024
#define DK 64
#define BB 4
#define SS 2048
#define NEG_INF -1000000000.0f

typedef _Float16 half8 __attribute__((ext_vector_type(8)));
typedef _Float16 half4 __attribute__((ext_vector_type(4)));
typedef float floatx4 __attribute__((ext_vector_type(4)));

// ---------------- weight transpose + fp32->fp16 ----------------
__global__ void transpose_w(const float* __restrict__ W, _Float16* __restrict__ WT) {
    __shared__ float tile[32][33];
    int n0 = blockIdx.x * 32;
    int k0 = blockIdx.y * 32;
    int tx = threadIdx.x;   // 0..31
    int ty = threadIdx.y;   // 0..7
    for (int i = ty; i < 32; i += 8)
        tile[i][tx] = W[(size_t)(k0 + i) * 1024 + n0 + tx];
    __syncthreads();
    for (int i = ty; i < 32; i += 8)
        WT[(size_t)(n0 + i) * 1024 + k0 + tx] = (_Float16)tile[tx][i];
}

// ---------------- LayerNorm row stats ----------------
__global__ void ln_stats(const float* __restrict__ q, float* __restrict__ mu_out,
                         float* __restrict__ rs_out) {
    int row = blockIdx.x;
    const float4* src = reinterpret_cast<const float4*>(q + (size_t)row * 1024);
    float4 v = src[threadIdx.x];
    float s  = v.x + v.y + v.z + v.w;
    float ss = v.x * v.x + v.y * v.y + v.z * v.z + v.w * v.w;
    for (int m = 1; m < 64; m <<= 1) { s += __shfl_xor(s, m); ss += __shfl_xor(ss, m); }
    __shared__ float as[4], ass[4];
    int w = threadIdx.x >> 6;
    if ((threadIdx.x & 63) == 0) { as[w] = s; ass[w] = ss; }
    __syncthreads();
    if (threadIdx.x == 0) {
        float S1 = as[0] + as[1] + as[2] + as[3];
        float S2 = ass[0] + ass[1] + ass[2] + ass[3];
        float mu = S1 * (1.0f / 1024.0f);
        float var = S2 * (1.0f / 1024.0f) - mu * mu;
        mu_out[row] = mu;
        rs_out[row] = rsqrtf(var + 1e-6f);
    }
}

// ---------------- projection / output GEMM ----------------
// MODE 0: qn@Wq (LN fused) -> qh [bh][s][64] fp16
// MODE 1: k@Wk            -> kh [bh][s][64] fp16
// MODE 2: v@Wv            -> vt [bh][64][s] fp16 (transposed for PV B-operand)
// MODE 3: oh@Wo + resid   -> out0 fp32
template <int MODE>
__global__ __launch_bounds__(256) void proj_gemm(
    const float* __restrict__ Af32, const _Float16* __restrict__ Af16,
    const _Float16* __restrict__ WT,  // [N][K] fp16
    const float* __restrict__ mu, const float* __restrict__ rs,
    const float* __restrict__ gamma, const float* __restrict__ beta,
    _Float16* __restrict__ outH, float* __restrict__ out0,
    const float* __restrict__ resid) {
    __shared__ _Float16 As[128][72];  // +8 pad: breaks pow2 bank stride
    __shared__ _Float16 Bs[128][72];

    int t = threadIdx.x;
    int warp = t >> 6, lane = t & 63;
    int l15 = lane & 15, quad = lane >> 4;
    int wr = (warp >> 1) * 64, wc = (warp & 1) * 64;
    int row0 = blockIdx.x * 128;
    int col0 = blockIdx.y * 128;

    floatx4 acc[4][4] = {};

    for (int k0 = 0; k0 < 1024; k0 += 64) {
        // stage A
        if (MODE <= 2) {
            for (int it = 0; it < 8; ++it) {
                int e = t + it * 256;       // float4 units, 2048 total
                int r = e >> 4;
                int c = (e & 15) * 4;
                int grow = row0 + r;
                float4 x = *reinterpret_cast<const float4*>(Af32 + (size_t)grow * 1024 + k0 + c);
                if (MODE == 0) {
                    float m_ = mu[grow], rr = rs[grow];
                    float4 g = *reinterpret_cast<const float4*>(gamma + k0 + c);
                    float4 b = *reinterpret_cast<const float4*>(beta + k0 + c);
                    x.x = (x.x - m_) * rr * g.x + b.x;
                    x.y = (x.y - m_) * rr * g.y + b.y;
                    x.z = (x.z - m_) * rr * g.z + b.z;
                    x.w = (x.w - m_) * rr * g.w + b.w;
                }
                half4 h;
                h[0] = (_Float16)x.x; h[1] = (_Float16)x.y;
                h[2] = (_Float16)x.z; h[3] = (_Float16)x.w;
                *reinterpret_cast<half4*>(&As[r][c]) = h;
            }
        } else {
            for (int it = 0; it < 4; ++it) {
                int e = t + it * 256;       // half8 units, 1024 total
                int r = e >> 3;
                int c = (e & 7) * 8;
                *reinterpret_cast<half8*>(&As[r][c]) =
                    *reinterpret_cast<const half8*>(Af16 + (size_t)(row0 + r) * 1024 + k0 + c);
            }
        }
        // stage B (W^T rows = output cols, K contiguous)
        for (int it = 0; it < 4; ++it) {
            int e = t + it * 256;
            int r = e >> 3;
            int c = (e & 7) * 8;
            *reinterpret_cast<half8*>(&Bs[r][c]) =
                *reinterpret_cast<const half8*>(WT + (size_t)(col0 + r) * 1024 + k0 + c);
        }
        __syncthreads();
        for (int ks = 0; ks < 2; ++ks) {
            half8 a[4], b[4];
            for (int i = 0; i < 4; ++i)
                a[i] = *reinterpret_cast<half8*>(&As[wr + i * 16 + l15][quad * 8 + ks * 32]);
            for (int j = 0; j < 4; ++j)
                b[j] = *reinterpret_cast<half8*>(&Bs[wc + j * 16 + l15][quad * 8 + ks * 32]);
            for (int i = 0; i < 4; ++i)
                for (int j = 0; j < 4; ++j)
                    acc[i][j] = __builtin_amdgcn_mfma_f32_16x16x32_f16(a[i], b[j], acc[i][j], 0, 0, 0);
        }
        __syncthreads();
    }

    // epilogue: C layout col=lane&15, row=quad*4+r
    for (int i = 0; i < 4; ++i)
        for (int j = 0; j < 4; ++j)
            for (int r = 0; r < 4; ++r) {
                int grow = row0 + wr + i * 16 + quad * 4 + r;
                int gcol = col0 + wc + j * 16 + l15;
                float val = acc[i][j][r];
                if (MODE == 0 || MODE == 1) {
                    int b_ = grow >> 11, s_ = grow & 2047;
                    int h_ = gcol >> 6, d_ = gcol & 63;
                    outH[(((size_t)(b_ * 16 + h_) * 2048 + s_) << 6) + d_] = (_Float16)val;
                } else if (MODE == 2) {
                    int b_ = grow >> 11, s_ = grow & 2047;
                    int h_ = gcol >> 6, d_ = gcol & 63;
                    outH[((size_t)(b_ * 16 + h_) * 64 + d_) * 2048 + s_] = (_Float16)val;
                } else {
                    out0[(size_t)grow * 1024 + gcol] = val + resid[(size_t)grow * 1024 + gcol];
                }
            }
}

// ---------------- flash-style attention, two passes ----------------
// PASS 1: online row max + sumexp (stats only)
// PASS 2: recompute logits (bit-identical), write normalized attn, accumulate P@V
template <int PASS>
__global__ __launch_bounds__(256) void attn_kernel(
    const _Float16* __restrict__ qh, const _Float16* __restrict__ kh,
    const _Float16* __restrict__ vt, const int* __restrict__ mask,
    float* __restrict__ stats_m, float* __restrict__ stats_l,
    float* __restrict__ attn_out, _Float16* __restrict__ oh) {
    __shared__ int smask[2048];
    __shared__ _Float16 pbuf[4][16][136];  // per-wave C->A layout bounce

    int bh = blockIdx.y;
    int b_ = bh >> 4, h_ = bh & 15;
    int t = threadIdx.x, warp = t >> 6, lane = t & 63;
    int l15 = lane & 15, quad = lane >> 4;
    int q0 = blockIdx.x * 64 + warp * 16;  // this wave's 16 query rows

    for (int i = t; i < 2048; i += 256) smask[i] = mask[b_ * 2048 + i];
    __syncthreads();

    // A-frags for Q rows (layout: row=lane&15, k=quad*8+j)
    const _Float16* qbase = qh + ((size_t)bh * 2048 + q0 + l15) * 64 + quad * 8;
    half8 aq0 = *reinterpret_cast<const half8*>(qbase);
    half8 aq1 = *reinterpret_cast<const half8*>(qbase + 32);

    float m_run[4], l_run[4], inv_l[4];
    if (PASS == 1) {
        for (int r = 0; r < 4; ++r) { m_run[r] = -INFINITY; l_run[r] = 0.0f; }
    } else {
        for (int r = 0; r < 4; ++r) {
            int row = q0 + quad * 4 + r;
            m_run[r] = stats_m[(size_t)bh * 2048 + row];
            inv_l[r] = 1.0f / stats_l[(size_t)bh * 2048 + row];
        }
    }
    floatx4 accpv[4] = {};

    for (int kv = 0; kv < 16; ++kv) {
        int colb = kv * 128;
        floatx4 lg[8];
        for (int g = 0; g < 8; ++g) {
            const _Float16* kbase =
                kh + ((size_t)bh * 2048 + colb + g * 16 + l15) * 64 + quad * 8;
            floatx4 a = {0.f, 0.f, 0.f, 0.f};
            a = __builtin_amdgcn_mfma_f32_16x16x32_f16(aq0, *reinterpret_cast<const half8*>(kbase), a, 0, 0, 0);
            a = __builtin_amdgcn_mfma_f32_16x16x32_f16(aq1, *reinterpret_cast<const half8*>(kbase + 32), a, 0, 0, 0);
            bool ok = smask[colb + g * 16 + l15] != 0;
            for (int r = 0; r < 4; ++r) lg[g][r] = ok ? a[r] * 0.125f : NEG_INF;
        }
        if (PASS == 1) {
            for (int r = 0; r < 4; ++r) {
                float tm = lg[0][r];
                for (int g = 1; g < 8; ++g) tm = fmaxf(tm, lg[g][r]);
                for (int m = 1; m < 16; m <<= 1) tm = fmaxf(tm, __shfl_xor(tm, m));
                float mn = fmaxf(m_run[r], tm);
                float se = 0.0f;
                for (int g = 0; g < 8; ++g) se += __expf(lg[g][r] - mn);
                for (int m = 1; m < 16; m <<= 1) se += __shfl_xor(se, m);
                l_run[r] = l_run[r] * __expf(m_run[r] - mn) + se;
                m_run[r] = mn;
            }
        } else {
            for (int g = 0; g < 8; ++g) {
                int col = colb + g * 16 + l15;
                for (int r = 0; r < 4; ++r) {
                    float p = __expf(lg[g][r] - m_run[r]) * inv_l[r];
                    attn_out[((size_t)bh * 2048 + q0 + quad * 4 + r) * 2048 + col] = p;
                    pbuf[warp][quad * 4 + r][g * 16 + l15] = (_Float16)p;
                }
            }
            __syncthreads();
            for (int ks = 0; ks < 4; ++ks) {
                half8 ap = *reinterpret_cast<half8*>(&pbuf[warp][l15][quad * 8 + ks * 32]);
                for (int dg = 0; dg < 4; ++dg) {
                    const _Float16* vbase =
                        vt + ((size_t)bh * 64 + dg * 16 + l15) * 2048 + colb + quad * 8 + ks * 32;
                    accpv[dg] = __builtin_amdgcn_mfma_f32_16x16x32_f16(
                        ap, *reinterpret_cast<const half8*>(vbase), accpv[dg], 0, 0, 0);
                }
            }
            __syncthreads();
        }
    }

    if (PASS == 1) {
        if (l15 == 0)
            for (int r = 0; r < 4; ++r) {
                int row = q0 + quad * 4 + r;
                stats_m[(size_t)bh * 2048 + row] = m_run[r];
                stats_l[(size_t)bh * 2048 + row] = l_run[r];
            }
    } else {
        for (int dg = 0; dg < 4; ++dg)
            for (int r = 0; r < 4; ++r) {
                int row = q0 + quad * 4 + r;
                oh[((size_t)b_ * 2048 + row) * 1024 + h_ * 64 + dg * 16 + l15] =
                    (_Float16)accpv[dg][r];
            }
    }
}

extern "C" void kernel_launch(void* const* d_in, const int* in_sizes, int n_in,
                              void* d_out, int out_size, void* d_ws, size_t ws_size,
                              hipStream_t stream) {
    const float* q     = (const float*)d_in[0];
    const float* k     = (const float*)d_in[1];
    const float* v     = (const float*)d_in[2];
    const int*   mask  = (const int*)d_in[3];
    const float* Wq    = (const float*)d_in[4];
    const float* Wk    = (const float*)d_in[5];
    const float* Wv    = (const float*)d_in[6];
    const float* Wo    = (const float*)d_in[7];
    const float* gamma = (const float*)d_in[8];
    const float* beta  = (const float*)d_in[9];

    char* ws = (char*)d_ws;
    _Float16* WqT = (_Float16*)(ws + 0);
    _Float16* WkT = (_Float16*)(ws + 2097152);
    _Float16* WvT = (_Float16*)(ws + 4194304);
    _Float16* WoT = (_Float16*)(ws + 6291456);
    float* muA    = (float*)(ws + 8388608);
    float* rsA    = (float*)(ws + 8421376);
    _Float16* qh  = (_Float16*)(ws + 8454144);
    _Float16* kh  = (_Float16*)(ws + 25231360);
    _Float16* vt  = (_Float16*)(ws + 42008576);
    _Float16* oh  = (_Float16*)(ws + 58785792);
    float* sm     = (float*)(ws + 75563008);
    float* sl     = (float*)(ws + 76087296);

    float* out0 = (float*)d_out;
    float* attn_out = (float*)d_out + (size_t)BB * SS * DM;  // 8388608 floats

    dim3 tb(32, 8);
    transpose_w<<<dim3(32, 32), tb, 0, stream>>>(Wq, WqT);
    transpose_w<<<dim3(32, 32), tb, 0, stream>>>(Wk, WkT);
    transpose_w<<<dim3(32, 32), tb, 0, stream>>>(Wv, WvT);
    transpose_w<<<dim3(32, 32), tb, 0, stream>>>(Wo, WoT);
    ln_stats<<<8192, 256, 0, stream>>>(q, muA, rsA);

    proj_gemm<0><<<dim3(64, 8), 256, 0, stream>>>(q, nullptr, WqT, muA, rsA, gamma, beta, qh, nullptr, nullptr);
    proj_gemm<1><<<dim3(64, 8), 256, 0, stream>>>(k, nullptr, WkT, nullptr, nullptr, nullptr, nullptr, kh, nullptr, nullptr);
    proj_gemm<2><<<dim3(64, 8), 256, 0, stream>>>(v, nullptr, WvT, nullptr, nullptr, nullptr, nullptr, vt, nullptr, nullptr);

    attn_kernel<1><<<dim3(32, 64), 256, 0, stream>>>(qh, kh, vt, mask, sm, sl, attn_out, oh);
    attn_kernel<2><<<dim3(32, 64), 256, 0, stream>>>(qh, kh, vt, mask, sm, sl, attn_out, oh);

    proj_gemm<3><<<dim3(64, 8), 256, 0, stream>>>(nullptr, oh, WoT, nullptr, nullptr, nullptr, nullptr, nullptr, out0, q);
}